// Round 2
// baseline (6996.262 us; speedup 1.0000x reference)
//
#include <hip/hip_runtime.h>
#include <stdint.h>

typedef __attribute__((ext_vector_type(8))) short bf16x8;
typedef __attribute__((ext_vector_type(4))) float f32x4;

__device__ __forceinline__ float bf2f(unsigned short u) {
    union { unsigned int u32; float f; } v; v.u32 = ((unsigned int)u) << 16; return v.f;
}
__device__ __forceinline__ unsigned short f2bf(float f) {
    union { float f; unsigned int u32; } v; v.f = f;
    unsigned int r = v.u32 + 0x7FFFu + ((v.u32 >> 16) & 1u);
    return (unsigned short)(r >> 16);
}
__device__ __forceinline__ float sigm(float x) { return 1.f / (1.f + __expf(-x)); }
__device__ __forceinline__ float tanh_fast(float x) {
    float ax = fabsf(x);
    float e = __expf(-2.f * ax);
    float t = (1.f - e) / (1.f + e);
    return copysignf(t, x);
}

// ---------------- fp32 -> bf16 convert (n4 = count of float4 groups) -------------
__global__ void f2bf_kernel(const float* __restrict__ src, unsigned short* __restrict__ dst, int n4) {
    int i = blockIdx.x * blockDim.x + threadIdx.x;
    if (i >= n4) return;
    float4 v = ((const float4*)src)[i];
    ushort4 o;
    o.x = f2bf(v.x); o.y = f2bf(v.y); o.z = f2bf(v.z); o.w = f2bf(v.w);
    ((ushort4*)dst)[i] = o;
}

// ---------------- combined bias: [2048] = fwd(bih+bhh) | rev(bih+bhh) ------------
__global__ void bias_comb_kernel(const float* __restrict__ bif, const float* __restrict__ bhf,
                                 const float* __restrict__ bir, const float* __restrict__ bhr,
                                 float* __restrict__ out) {
    int n = blockIdx.x * blockDim.x + threadIdx.x;
    if (n >= 2048) return;
    out[n] = (n < 1024) ? (bif[n] + bhf[n]) : (bir[n - 1024] + bhr[n - 1024]);
}

// ---------------- GEMM: C[m,n](bf16) = sum_k A[m,k]*B[n,k] + bias[n] -------------
__global__ __launch_bounds__(256, 2) void gemm_bt_bias(
    const unsigned short* __restrict__ A, const unsigned short* __restrict__ B,
    const float* __restrict__ bias, unsigned short* __restrict__ C,
    int M, int N, int K) {
    const int bn0 = blockIdx.x * 128;
    const int bm0 = blockIdx.y * 128;
    const int tid = threadIdx.x;
    const int wave = tid >> 6, lane = tid & 63;
    const int ln15 = lane & 15, quad = lane >> 4;
    const int wr = wave >> 1, wc = wave & 1;

    __shared__ __align__(16) unsigned short At[128 * 72];
    __shared__ __align__(16) unsigned short Bt[128 * 72];

    f32x4 acc[4][4] = {};

    for (int ko = 0; ko < K; ko += 64) {
#pragma unroll
        for (int i = 0; i < 4; ++i) {
            int chunk = tid + i * 256;
            int row = chunk >> 3, cc = chunk & 7;
            *(bf16x8*)&At[row * 72 + cc * 8] = *(const bf16x8*)&A[(size_t)(bm0 + row) * K + ko + cc * 8];
            *(bf16x8*)&Bt[row * 72 + cc * 8] = *(const bf16x8*)&B[(size_t)(bn0 + row) * K + ko + cc * 8];
        }
        __syncthreads();
#pragma unroll
        for (int kk = 0; kk < 2; ++kk) {
            bf16x8 a[4], b[4];
#pragma unroll
            for (int f = 0; f < 4; ++f) {
                a[f] = *(const bf16x8*)&At[(wr * 64 + f * 16 + ln15) * 72 + kk * 32 + quad * 8];
                b[f] = *(const bf16x8*)&Bt[(wc * 64 + f * 16 + ln15) * 72 + kk * 32 + quad * 8];
            }
#pragma unroll
            for (int fi = 0; fi < 4; ++fi)
#pragma unroll
                for (int fj = 0; fj < 4; ++fj)
                    acc[fi][fj] = __builtin_amdgcn_mfma_f32_16x16x32_bf16(a[fi], b[fj], acc[fi][fj], 0, 0, 0);
        }
        __syncthreads();
    }
#pragma unroll
    for (int fi = 0; fi < 4; ++fi) {
        int row = bm0 + wr * 64 + fi * 16 + quad * 4;
#pragma unroll
        for (int fj = 0; fj < 4; ++fj) {
            int col = bn0 + wc * 64 + fj * 16 + ln15;
            float bv = bias[col];
#pragma unroll
            for (int r = 0; r < 4; ++r)
                C[(size_t)(row + r) * N + col] = f2bf(acc[fi][fj][r] + bv);
        }
    }
}

// ---------------- persistent LSTM scan, N-split with LDS-resident Whh ------------
// Grid = 128 WGs: cg = b&3 (64 h-cols), bg = (b>>2)&15 (16 batch rows), dir = b>>6.
// Each WG keeps its 256 Whh rows (4 gates x 64 cols) in LDS for all 160 steps.
// h exchanged via global double-buffer hexg[slot][dir][bg][16][256] (bf16);
// group barrier = counter ctr[dir][bg][t], 4 arrivals (the 4 cg WGs).
// Wave w computes gate w (rows w*64..w*64+63 of the WG's 256 gate rows).
__global__ __launch_bounds__(256, 1) void lstm_scan2(
    const unsigned short* __restrict__ xg,      // [T*B, 2048] bf16
    const unsigned short* __restrict__ whh_f,   // [1024,256] bf16
    const unsigned short* __restrict__ whh_r,   // [1024,256] bf16
    unsigned short* __restrict__ out_bf,        // [T,B,512] bf16 (layer0) or null
    float* __restrict__ out_f,                  // [T,B,512] f32 (layer1) or null
    unsigned short* __restrict__ hexg,          // [2][2][16][16][256] bf16 (zeroed)
    int* __restrict__ ctr)                      // [2][16][160] int (zeroed)
{
    const int b = blockIdx.x;
    const int cg = b & 3, bg = (b >> 2) & 15, dir = b >> 6;
    const int m0 = bg * 16;
    const int tid = threadIdx.x;
    const int wave = tid >> 6, lane = tid & 63;
    const int ln15 = lane & 15, quad = lane >> 4;
    const unsigned short* __restrict__ whh = dir ? whh_r : whh_f;
    int* __restrict__ cptr = ctr + (dir * 16 + bg) * 160;

    __shared__ __align__(16) unsigned short wsh[256 * 264];  // Whh slice, pad 264
    __shared__ float gbuf[16 * 260];                         // gate bounce [m][g*64+jj]

    // one-time Whh slice load: LDS row wrow = g*64+jj  <- global row g*256+cg*64+jj
    for (int idx = tid; idx < 8192; idx += 256) {
        int wrow = idx >> 5, cc = idx & 31;
        int g = wrow >> 6, jj = wrow & 63;
        *(bf16x8*)&wsh[wrow * 264 + cc * 8] =
            *(const bf16x8*)&whh[(size_t)(g * 256 + cg * 64 + jj) * 256 + cc * 8];
    }
    __syncthreads();

    // per-thread cell state: m = tid>>4, jj = (tid&15) + p*16
    const int cm = tid >> 4, cj = tid & 15;
    float c[4] = {0.f, 0.f, 0.f, 0.f};

    for (int tt = 0; tt < 160; ++tt) {
        const int t = dir ? (159 - tt) : tt;

        // acc init from xg (independent of h -> issue before the barrier spin)
        f32x4 acc[4];
        {
            const unsigned short* xr = xg + (size_t)(t * 256 + m0 + quad * 4) * 2048
                                          + dir * 1024 + wave * 256 + cg * 64 + ln15;
#pragma unroll
            for (int nt = 0; nt < 4; ++nt)
#pragma unroll
                for (int r = 0; r < 4; ++r)
                    acc[nt][r] = bf2f(xr[(size_t)r * 2048 + nt * 16]);
        }

        // wait for all 4 WGs of this (dir,bg) group to publish h_{t-1}
        if (tt > 0) {
            if (tid == 0) {
                int lim = 1 << 20;
                while (__hip_atomic_load(cptr + (tt - 1), __ATOMIC_ACQUIRE,
                                         __HIP_MEMORY_SCOPE_AGENT) < 4 && --lim) { }
            }
            __syncthreads();
        }

        // A-fragments: h_{t-1} from exchange buffer slot (tt-1)&1 (slot1 holds zeros at tt=0)
        const int slot_r = (tt + 1) & 1;
        const unsigned short* hsrc = hexg + (size_t)(((slot_r * 2 + dir) * 16 + bg)) * 4096;
        bf16x8 af[8];
#pragma unroll
        for (int kb = 0; kb < 8; ++kb)
            af[kb] = *(const bf16x8*)&hsrc[ln15 * 256 + kb * 32 + quad * 8];

        // GEMM: gates[m, w*64+nt*16+ln15] += sum_k h[m,k] * Whh_slice
#pragma unroll
        for (int kb = 0; kb < 8; ++kb) {
#pragma unroll
            for (int nt = 0; nt < 4; ++nt) {
                bf16x8 bfrag = *(const bf16x8*)&wsh[(wave * 64 + nt * 16 + ln15) * 264 + kb * 32 + quad * 8];
                acc[nt] = __builtin_amdgcn_mfma_f32_16x16x32_bf16(af[kb], bfrag, acc[nt], 0, 0, 0);
            }
        }

        // activation (wave-uniform gate) + bounce to LDS
#pragma unroll
        for (int nt = 0; nt < 4; ++nt)
#pragma unroll
            for (int r = 0; r < 4; ++r) {
                float v = acc[nt][r];
                v = (wave == 2) ? tanh_fast(v) : sigm(v);
                gbuf[(quad * 4 + r) * 260 + wave * 64 + nt * 16 + ln15] = v;
            }
        __syncthreads();

        // cell update: 4 (m,jj) pairs per thread; write h to exchange slot tt&1 + output
        const int slot_w = tt & 1;
        unsigned short* hdst = hexg + (size_t)(((slot_w * 2 + dir) * 16 + bg)) * 4096;
        const float* gb = gbuf + cm * 260;
#pragma unroll
        for (int p = 0; p < 4; ++p) {
            int jj = cj + p * 16;
            float iv = gb[jj];
            float fv = gb[64 + jj];
            float gv = gb[128 + jj];
            float ov = gb[192 + jj];
            float cn = fv * c[p] + iv * gv;
            c[p] = cn;
            float hv = ov * tanh_fast(cn);
            unsigned short hb = f2bf(hv);
            hdst[cm * 256 + cg * 64 + jj] = hb;
            size_t oidx = (size_t)(t * 256 + m0 + cm) * 512 + dir * 256 + cg * 64 + jj;
            if (out_f) out_f[oidx] = hv;
            else out_bf[oidx] = hb;
        }

        // publish: fence, then one arrival per WG
        __threadfence();
        __syncthreads();
        if (tid == 0)
            __hip_atomic_fetch_add(cptr + tt, 1, __ATOMIC_ACQ_REL, __HIP_MEMORY_SCOPE_AGENT);
    }
}

// ---------------- host-side launch -----------------------------------------------
extern "C" void kernel_launch(void* const* d_in, const int* in_sizes, int n_in,
                              void* d_out, int out_size, void* d_ws, size_t ws_size,
                              hipStream_t stream) {
    const float* x = (const float*)d_in[0];
    float* out = (float*)d_out;
    char* ws = (char*)d_ws;

    // workspace layout (bytes, 256-aligned)
    unsigned short* xbf   = (unsigned short*)(ws + 0);            // 40960x512 bf16 = 41,943,040
    unsigned short* wcat0 = (unsigned short*)(ws + 41943040LL);   // 2048x512 bf16
    unsigned short* wcat1 = (unsigned short*)(ws + 44040192LL);   // 2048x512 bf16
    unsigned short* whh0f = (unsigned short*)(ws + 46137344LL);   // 4 x 1024x256 bf16
    unsigned short* whh0r = whh0f + 262144;
    unsigned short* whh1f = whh0f + 524288;
    unsigned short* whh1r = whh0f + 786432;
    float* bias0          = (float*)(ws + 48234496LL);            // 2048 f32
    float* bias1          = (float*)(ws + 48242688LL);            // 2048 f32
    unsigned short* xgbuf = (unsigned short*)(ws + 48250880LL);   // 40960x2048 bf16 = 167,772,160
    unsigned short* hexg  = (unsigned short*)(ws + 216023040LL);  // 524,288 B
    int* ctrbuf           = (int*)(ws + 216547328LL);             // 20,480 B
    unsigned short* h0b   = xbf;  // reuse: xbf dead after GEMM L0
    // total: ~216.6 MB

    // ---- prep: converts + bias combine ----
    f2bf_kernel<<<20480, 256, 0, stream>>>(x, xbf, 5242880);
    f2bf_kernel<<<512, 256, 0, stream>>>((const float*)d_in[1], wcat0, 131072);
    f2bf_kernel<<<512, 256, 0, stream>>>((const float*)d_in[5], wcat0 + 524288, 131072);
    f2bf_kernel<<<512, 256, 0, stream>>>((const float*)d_in[9], wcat1, 131072);
    f2bf_kernel<<<512, 256, 0, stream>>>((const float*)d_in[13], wcat1 + 524288, 131072);
    f2bf_kernel<<<256, 256, 0, stream>>>((const float*)d_in[2], whh0f, 65536);
    f2bf_kernel<<<256, 256, 0, stream>>>((const float*)d_in[6], whh0r, 65536);
    f2bf_kernel<<<256, 256, 0, stream>>>((const float*)d_in[10], whh1f, 65536);
    f2bf_kernel<<<256, 256, 0, stream>>>((const float*)d_in[14], whh1r, 65536);
    bias_comb_kernel<<<8, 256, 0, stream>>>((const float*)d_in[3], (const float*)d_in[4],
                                            (const float*)d_in[7], (const float*)d_in[8], bias0);
    bias_comb_kernel<<<8, 256, 0, stream>>>((const float*)d_in[11], (const float*)d_in[12],
                                            (const float*)d_in[15], (const float*)d_in[16], bias1);

    dim3 gg(16, 320);  // N/128 x M/128
    // ---- layer 0 ----
    gemm_bt_bias<<<gg, 256, 0, stream>>>(xbf, wcat0, bias0, xgbuf, 40960, 2048, 512);
    hipMemsetAsync(hexg, 0, 524288, stream);
    hipMemsetAsync(ctrbuf, 0, 20480, stream);
    lstm_scan2<<<128, 256, 0, stream>>>(xgbuf, whh0f, whh0r, h0b, nullptr, hexg, ctrbuf);
    // ---- layer 1 ----
    gemm_bt_bias<<<gg, 256, 0, stream>>>(h0b, wcat1, bias1, xgbuf, 40960, 2048, 512);
    hipMemsetAsync(hexg, 0, 524288, stream);
    hipMemsetAsync(ctrbuf, 0, 20480, stream);
    lstm_scan2<<<128, 256, 0, stream>>>(xgbuf, whh1f, whh1r, nullptr, out, hexg, ctrbuf);
}

// Round 3
// 1776.956 us; speedup vs baseline: 3.9372x; 3.9372x over previous
//
#include <hip/hip_runtime.h>
#include <stdint.h>

typedef __attribute__((ext_vector_type(8))) short bf16x8;
typedef __attribute__((ext_vector_type(4))) float f32x4;

__device__ __forceinline__ float bf2f(unsigned short u) {
    union { unsigned int u32; float f; } v; v.u32 = ((unsigned int)u) << 16; return v.f;
}
__device__ __forceinline__ unsigned short f2bf(float f) {
    union { float f; unsigned int u32; } v; v.f = f;
    unsigned int r = v.u32 + 0x7FFFu + ((v.u32 >> 16) & 1u);
    return (unsigned short)(r >> 16);
}
__device__ __forceinline__ float sigm(float x) { return 1.f / (1.f + __expf(-x)); }
__device__ __forceinline__ float tanh_fast(float x) {
    float ax = fabsf(x);
    float e = __expf(-2.f * ax);
    float t = (1.f - e) / (1.f + e);
    return copysignf(t, x);
}

// ---------------- fp32 -> bf16 convert (n4 = count of float4 groups) -------------
__global__ void f2bf_kernel(const float* __restrict__ src, unsigned short* __restrict__ dst, int n4) {
    int i = blockIdx.x * blockDim.x + threadIdx.x;
    if (i >= n4) return;
    float4 v = ((const float4*)src)[i];
    ushort4 o;
    o.x = f2bf(v.x); o.y = f2bf(v.y); o.z = f2bf(v.z); o.w = f2bf(v.w);
    ((ushort4*)dst)[i] = o;
}

// ---------------- combined bias: [2048] = fwd(bih+bhh) | rev(bih+bhh) ------------
__global__ void bias_comb_kernel(const float* __restrict__ bif, const float* __restrict__ bhf,
                                 const float* __restrict__ bir, const float* __restrict__ bhr,
                                 float* __restrict__ out) {
    int n = blockIdx.x * blockDim.x + threadIdx.x;
    if (n >= 2048) return;
    out[n] = (n < 1024) ? (bif[n] + bhf[n]) : (bir[n - 1024] + bhr[n - 1024]);
}

// ---------------- GEMM: C[m,n](bf16) = sum_k A[m,k]*B[n,k] + bias[n] -------------
__global__ __launch_bounds__(256, 2) void gemm_bt_bias(
    const unsigned short* __restrict__ A, const unsigned short* __restrict__ B,
    const float* __restrict__ bias, unsigned short* __restrict__ C,
    int M, int N, int K) {
    const int bn0 = blockIdx.x * 128;
    const int bm0 = blockIdx.y * 128;
    const int tid = threadIdx.x;
    const int wave = tid >> 6, lane = tid & 63;
    const int ln15 = lane & 15, quad = lane >> 4;
    const int wr = wave >> 1, wc = wave & 1;

    __shared__ __align__(16) unsigned short At[128 * 72];
    __shared__ __align__(16) unsigned short Bt[128 * 72];

    f32x4 acc[4][4] = {};

    for (int ko = 0; ko < K; ko += 64) {
#pragma unroll
        for (int i = 0; i < 4; ++i) {
            int chunk = tid + i * 256;
            int row = chunk >> 3, cc = chunk & 7;
            *(bf16x8*)&At[row * 72 + cc * 8] = *(const bf16x8*)&A[(size_t)(bm0 + row) * K + ko + cc * 8];
            *(bf16x8*)&Bt[row * 72 + cc * 8] = *(const bf16x8*)&B[(size_t)(bn0 + row) * K + ko + cc * 8];
        }
        __syncthreads();
#pragma unroll
        for (int kk = 0; kk < 2; ++kk) {
            bf16x8 a[4], b[4];
#pragma unroll
            for (int f = 0; f < 4; ++f) {
                a[f] = *(const bf16x8*)&At[(wr * 64 + f * 16 + ln15) * 72 + kk * 32 + quad * 8];
                b[f] = *(const bf16x8*)&Bt[(wc * 64 + f * 16 + ln15) * 72 + kk * 32 + quad * 8];
            }
#pragma unroll
            for (int fi = 0; fi < 4; ++fi)
#pragma unroll
                for (int fj = 0; fj < 4; ++fj)
                    acc[fi][fj] = __builtin_amdgcn_mfma_f32_16x16x32_bf16(a[fi], b[fj], acc[fi][fj], 0, 0, 0);
        }
        __syncthreads();
    }
#pragma unroll
    for (int fi = 0; fi < 4; ++fi) {
        int row = bm0 + wr * 64 + fi * 16 + quad * 4;
#pragma unroll
        for (int fj = 0; fj < 4; ++fj) {
            int col = bn0 + wc * 64 + fj * 16 + ln15;
            float bv = bias[col];
#pragma unroll
            for (int r = 0; r < 4; ++r)
                C[(size_t)(row + r) * N + col] = f2bf(acc[fi][fj][r] + bv);
        }
    }
}

// ---------------- persistent LSTM scan v3: fence-free N-split --------------------
// 128 WGs: gid = b&31 (group: dir=gid&1, bg=gid>>1), cg = b>>5 (64 gate-cols).
// Members of a group are blockIdx ≡ gid (mod 8) -> same XCD (perf heuristic only).
// Whh fragments (wave's 64 gate rows x 256 K = 32 KB) live in VGPRs all 160 steps.
// h exchange: relaxed agent-scope u64 atomics (per-access sc1 coherence, NO fences).
// Ordering: __syncthreads drains vmcnt before tid0's arrival fetch_add.
__global__ __launch_bounds__(256, 1) void lstm_scan3(
    const unsigned short* __restrict__ xg,      // [T*B, 2048] bf16
    const unsigned short* __restrict__ whh_f,   // [1024,256] bf16
    const unsigned short* __restrict__ whh_r,   // [1024,256] bf16
    unsigned short* __restrict__ out_bf,        // [T,B,512] bf16 (layer0) or null
    float* __restrict__ out_f,                  // [T,B,512] f32 (layer1) or null
    unsigned short* __restrict__ hexg,          // [2][2][16][16][256] bf16 (zeroed)
    int* __restrict__ ctr)                      // [2][16][160] int (zeroed)
{
    const int gid = blockIdx.x & 31;
    const int cg = blockIdx.x >> 5;
    const int dir = gid & 1, bg = gid >> 1;
    const int m0 = bg * 16;
    const int tid = threadIdx.x;
    const int wave = tid >> 6, lane = tid & 63;
    const int ln15 = lane & 15, quad = lane >> 4;
    const unsigned short* __restrict__ whh = dir ? whh_r : whh_f;
    int* __restrict__ cptr = ctr + (dir * 16 + bg) * 160;

    __shared__ float gbuf[16 * 260];   // gate bounce [m][g*64 + jj]

    // ---- one-time: load this wave's Whh fragments into registers (128 VGPRs) ----
    // wave computes gate g=wave for cols cg*64..cg*64+63.
    bf16x8 Bfr[32];
#pragma unroll
    for (int kb = 0; kb < 8; ++kb)
#pragma unroll
        for (int nt = 0; nt < 4; ++nt)
            Bfr[kb * 4 + nt] = *(const bf16x8*)&whh[
                (size_t)(wave * 256 + cg * 64 + nt * 16 + ln15) * 256 + kb * 32 + quad * 8];

    // cell mapping: thread (cm=tid>>4, cj=tid&15) owns row cm, cols cg*64+cj*4..+3
    const int cm = tid >> 4, cj = tid & 15;
    float c[4] = {0.f, 0.f, 0.f, 0.f};

    unsigned long long* hex64 = (unsigned long long*)hexg;

    for (int tt = 0; tt < 160; ++tt) {
        const int t = dir ? (159 - tt) : tt;

        // xg prefetch into acc (plain cached loads, issued before the spin)
        f32x4 acc[4];
        {
            const unsigned short* xr = xg + (size_t)(t * 256 + m0 + quad * 4) * 2048
                                          + dir * 1024 + wave * 256 + cg * 64 + ln15;
#pragma unroll
            for (int nt = 0; nt < 4; ++nt)
#pragma unroll
                for (int r = 0; r < 4; ++r)
                    acc[nt][r] = bf2f(xr[(size_t)r * 2048 + nt * 16]);
        }

        // wait for all 4 WGs of this group to have published h_{t-1}
        if (tt > 0) {
            if (tid == 0) {
                int lim = 1 << 22;
                while (__hip_atomic_load(cptr + (tt - 1), __ATOMIC_RELAXED,
                                         __HIP_MEMORY_SCOPE_AGENT) < 4 && --lim) { }
            }
            __syncthreads();
        }

        // A-fragments: h_{t-1} via relaxed agent-scope u64 loads (cache-bypassing)
        const int slot_r = (tt + 1) & 1;
        unsigned long long* hsrc = hex64 + (size_t)((slot_r * 2 + dir) * 16 + bg) * 1024;
        bf16x8 af[8];
#pragma unroll
        for (int kb = 0; kb < 8; ++kb) {
            union { unsigned long long u[2]; bf16x8 v; } tm;
            unsigned long long* p = hsrc + ln15 * 64 + kb * 8 + quad * 2;
            tm.u[0] = __hip_atomic_load(p, __ATOMIC_RELAXED, __HIP_MEMORY_SCOPE_AGENT);
            tm.u[1] = __hip_atomic_load(p + 1, __ATOMIC_RELAXED, __HIP_MEMORY_SCOPE_AGENT);
            af[kb] = tm.v;
        }

        // recurrent GEMM: 32 MFMAs, B from registers
#pragma unroll
        for (int kb = 0; kb < 8; ++kb)
#pragma unroll
            for (int nt = 0; nt < 4; ++nt)
                acc[nt] = __builtin_amdgcn_mfma_f32_16x16x32_bf16(af[kb], Bfr[kb * 4 + nt], acc[nt], 0, 0, 0);

        // activation (wave-uniform gate) + bounce to LDS
#pragma unroll
        for (int nt = 0; nt < 4; ++nt)
#pragma unroll
            for (int r = 0; r < 4; ++r) {
                float v = acc[nt][r];
                v = (wave == 2) ? tanh_fast(v) : sigm(v);
                gbuf[(quad * 4 + r) * 260 + wave * 64 + nt * 16 + ln15] = v;
            }
        __syncthreads();

        // cell update: 4 consecutive cols per thread
        const int slot_w = tt & 1;
        unsigned long long* hdst = hex64 + (size_t)((slot_w * 2 + dir) * 16 + bg) * 1024;
        const float* gb = gbuf + cm * 260;
        float hv[4];
#pragma unroll
        for (int p = 0; p < 4; ++p) {
            int jj = cg * 64 + cj * 4 + p;
            float iv = gb[jj];
            float fv = gb[256 + jj - 192];      // f gate at gbuf col 64 + (jj - cg*64)... see note
            // NOTE: gbuf cols are g*64 + local index within this WG's 64-col slice
            (void)iv; (void)fv;
            hv[p] = 0.f; // placeholder, replaced below
        }
        // gbuf col layout: gate g occupies [g*64, g*64+64) with local col = nt*16+ln15
        // == (global col - cg*64). Our cell cols local index = cj*4+p.
#pragma unroll
        for (int p = 0; p < 4; ++p) {
            int lj = cj * 4 + p;
            float iv = gb[lj];
            float fv = gb[64 + lj];
            float gv = gb[128 + lj];
            float ov = gb[192 + lj];
            float cn = fv * c[p] + iv * gv;
            c[p] = cn;
            hv[p] = ov * tanh_fast(cn);
        }
        unsigned long long pk = (unsigned long long)f2bf(hv[0])
                              | ((unsigned long long)f2bf(hv[1]) << 16)
                              | ((unsigned long long)f2bf(hv[2]) << 32)
                              | ((unsigned long long)f2bf(hv[3]) << 48);
        __hip_atomic_store(hdst + cm * 64 + cg * 16 + cj, pk,
                           __ATOMIC_RELAXED, __HIP_MEMORY_SCOPE_AGENT);

        // __syncthreads drains vmcnt(0) for every thread before s_barrier, so the
        // h stores of ALL threads have reached the coherence point before arrival.
        __syncthreads();
        if (tid == 0)
            __hip_atomic_fetch_add(cptr + tt, 1, __ATOMIC_RELAXED, __HIP_MEMORY_SCOPE_AGENT);

        // outputs AFTER arrival -> off the critical path (drain during next spin)
        size_t obase = (size_t)(t * 256 + m0 + cm) * 512 + dir * 256 + cg * 64 + cj * 4;
        if (out_f) {
            float4 o4; o4.x = hv[0]; o4.y = hv[1]; o4.z = hv[2]; o4.w = hv[3];
            *(float4*)&out_f[obase] = o4;
        } else {
            ushort4 o4;
            o4.x = f2bf(hv[0]); o4.y = f2bf(hv[1]); o4.z = f2bf(hv[2]); o4.w = f2bf(hv[3]);
            *(ushort4*)&out_bf[obase] = o4;
        }
    }
}

// ---------------- host-side launch -----------------------------------------------
extern "C" void kernel_launch(void* const* d_in, const int* in_sizes, int n_in,
                              void* d_out, int out_size, void* d_ws, size_t ws_size,
                              hipStream_t stream) {
    const float* x = (const float*)d_in[0];
    float* out = (float*)d_out;
    char* ws = (char*)d_ws;

    // workspace layout (bytes, 256-aligned)
    unsigned short* xbf   = (unsigned short*)(ws + 0);            // 40960x512 bf16 = 41,943,040
    unsigned short* wcat0 = (unsigned short*)(ws + 41943040LL);   // 2048x512 bf16
    unsigned short* wcat1 = (unsigned short*)(ws + 44040192LL);   // 2048x512 bf16
    unsigned short* whh0f = (unsigned short*)(ws + 46137344LL);   // 4 x 1024x256 bf16
    unsigned short* whh0r = whh0f + 262144;
    unsigned short* whh1f = whh0f + 524288;
    unsigned short* whh1r = whh0f + 786432;
    float* bias0          = (float*)(ws + 48234496LL);            // 2048 f32
    float* bias1          = (float*)(ws + 48242688LL);            // 2048 f32
    unsigned short* xgbuf = (unsigned short*)(ws + 48250880LL);   // 40960x2048 bf16 = 167,772,160
    unsigned short* hexg  = (unsigned short*)(ws + 216023040LL);  // 524,288 B
    int* ctrbuf           = (int*)(ws + 216547328LL);             // 20,480 B
    unsigned short* h0b   = xbf;  // reuse: xbf dead after GEMM L0 (kernel-boundary coherence)

    // ---- prep: converts + bias combine ----
    f2bf_kernel<<<20480, 256, 0, stream>>>(x, xbf, 5242880);
    f2bf_kernel<<<512, 256, 0, stream>>>((const float*)d_in[1], wcat0, 131072);
    f2bf_kernel<<<512, 256, 0, stream>>>((const float*)d_in[5], wcat0 + 524288, 131072);
    f2bf_kernel<<<512, 256, 0, stream>>>((const float*)d_in[9], wcat1, 131072);
    f2bf_kernel<<<512, 256, 0, stream>>>((const float*)d_in[13], wcat1 + 524288, 131072);
    f2bf_kernel<<<256, 256, 0, stream>>>((const float*)d_in[2], whh0f, 65536);
    f2bf_kernel<<<256, 256, 0, stream>>>((const float*)d_in[6], whh0r, 65536);
    f2bf_kernel<<<256, 256, 0, stream>>>((const float*)d_in[10], whh1f, 65536);
    f2bf_kernel<<<256, 256, 0, stream>>>((const float*)d_in[14], whh1r, 65536);
    bias_comb_kernel<<<8, 256, 0, stream>>>((const float*)d_in[3], (const float*)d_in[4],
                                            (const float*)d_in[7], (const float*)d_in[8], bias0);
    bias_comb_kernel<<<8, 256, 0, stream>>>((const float*)d_in[11], (const float*)d_in[12],
                                            (const float*)d_in[15], (const float*)d_in[16], bias1);

    dim3 gg(16, 320);  // N/128 x M/128
    // ---- layer 0 ----
    gemm_bt_bias<<<gg, 256, 0, stream>>>(xbf, wcat0, bias0, xgbuf, 40960, 2048, 512);
    hipMemsetAsync(hexg, 0, 524288, stream);
    hipMemsetAsync(ctrbuf, 0, 20480, stream);
    lstm_scan3<<<128, 256, 0, stream>>>(xgbuf, whh0f, whh0r, h0b, nullptr, hexg, ctrbuf);
    // ---- layer 1 ----
    gemm_bt_bias<<<gg, 256, 0, stream>>>(h0b, wcat1, bias1, xgbuf, 40960, 2048, 512);
    hipMemsetAsync(hexg, 0, 524288, stream);
    hipMemsetAsync(ctrbuf, 0, 20480, stream);
    lstm_scan3<<<128, 256, 0, stream>>>(xgbuf, whh1f, whh1r, nullptr, out, hexg, ctrbuf);
}